// Round 8
// baseline (72.048 us; speedup 1.0000x reference)
//
#include <hip/hip_runtime.h>

#define BATCH      4096
#define NCLS       32
#define NCLASSES   512
#define EMBD       128
#define NEMB       16384                 // NCLS * NCLASSES
#define NROWS      (BATCH * NCLS)        // 131072
#define TRBLOCKS   ((NEMB / 32) * (EMBD / 32))   // 2048 transpose blocks
#define BBLOCKS    (NROWS / 8)           // 16384 gather blocks

typedef float f4 __attribute__((ext_vector_type(4)));

// ---------------------------------------------------------------------------
// Kernel A: heterogeneous grid (identical to R6).
//   blocks [0, TRBLOCKS)          : transpose emb (EMBD x NEMB) -> embT
//   blocks [TRBLOCKS, +NROWS/8)   : streaming argmax, half-wave per row
// Plain (non-NT) loads: R6 A/B showed nt costs ~4.6us on the read stream.
// ---------------------------------------------------------------------------
__global__ __launch_bounds__(256) void vq_tr_argmax(
    const float* __restrict__ onehot, const float* __restrict__ emb,
    float* __restrict__ embT, int* __restrict__ idxout) {

    if (blockIdx.x < TRBLOCKS) {
        __shared__ float tile[32][33];
        const int e0 = (blockIdx.x & (NEMB / 32 - 1)) * 32;
        const int d0 = (blockIdx.x / (NEMB / 32)) * 32;
        const int tx = threadIdx.x & 31;
        const int ty = threadIdx.x >> 5;
#pragma unroll
        for (int k = 0; k < 32; k += 8)
            tile[ty + k][tx] = emb[(size_t)(d0 + ty + k) * NEMB + (e0 + tx)];
        __syncthreads();
#pragma unroll
        for (int k = 0; k < 32; k += 8)
            embT[(size_t)(e0 + ty + k) * EMBD + (d0 + tx)] = tile[tx][ty + k];
        return;
    }

    const int ab   = blockIdx.x - TRBLOCKS;
    const int wave = threadIdx.x >> 6;
    const int lane = threadIdx.x & 63;
    const int half = lane >> 5;
    const int hl   = lane & 31;
    const int r    = (ab * 4 + wave) * 2 + half;
    const float* row = onehot + (size_t)r * NCLASSES;

    float v  = -INFINITY;
    int   vi = 0;
#pragma unroll
    for (int k = 0; k < 4; ++k) {
        const int base = hl * 4 + k * 128;
        const f4 x = *reinterpret_cast<const f4*>(row + base);   // plain load
#pragma unroll
        for (int j = 0; j < 4; ++j) {
            if (x[j] > v) { v = x[j]; vi = base + j; }   // strict >: first wins
        }
    }
#pragma unroll
    for (int off = 16; off > 0; off >>= 1) {
        const float ov = __shfl_xor(v, off);
        const int   oi = __shfl_xor(vi, off);
        if (ov > v || (ov == v && oi < vi)) { v = ov; vi = oi; }
    }
    if (hl == 0) idxout[r] = vi;
}

// ---------------------------------------------------------------------------
// Kernel B: gather + write, c-clustered XCD swizzle.
// R8 A/B vs R6: output store is PLAIN (was nontemporal). NT-load cost ~4.6us
// on the read stream in R6; testing whether NT-store similarly throttles the
// 67MB write stream (fills hit 7.1 TB/s with normal stores).
// ---------------------------------------------------------------------------
__global__ __launch_bounds__(256) void vq_gather(
    const int* __restrict__ idx, const float* __restrict__ embT,
    float* __restrict__ out) {
    const int xcd  = blockIdx.x & 7;
    const int slot = blockIdx.x >> 3;                 // 0..2047
    const int g    = xcd >> 1;                        // c-group 0..3
    const int w    = g + 4 * ((xcd & 1) * (BBLOCKS / 8) + slot);  // bijective

    const int wave = threadIdx.x >> 6;
    const int lane = threadIdx.x & 63;
    const int half = lane >> 5;
    const int hl   = lane & 31;
    const int r    = (w * 4 + wave) * 2 + half;

    const int c    = r & (NCLS - 1);
    const int flat = idx[r] + c * NCLASSES;   // uniform per half: broadcast load

    const f4 val = reinterpret_cast<const f4*>(embT + (size_t)flat * EMBD)[hl];
    reinterpret_cast<f4*>(out + (size_t)r * EMBD)[hl] = val;   // plain store
}

// ---------------------------------------------------------------------------
// Fallback (ws too small): fused argmax + direct column gather.
// ---------------------------------------------------------------------------
__global__ __launch_bounds__(256) void vq_fused_cols(
    const float* __restrict__ onehot, const float* __restrict__ emb,
    float* __restrict__ out) {
    const int wave = threadIdx.x >> 6;
    const int lane = threadIdx.x & 63;
    const int half = lane >> 5;
    const int hl   = lane & 31;
    const int r    = (blockIdx.x * 4 + wave) * 2 + half;
    const float* row = onehot + (size_t)r * NCLASSES;

    float v  = -INFINITY;
    int   vi = 0;
#pragma unroll
    for (int k = 0; k < 4; ++k) {
        const int base = hl * 4 + k * 128;
        const f4 x = *reinterpret_cast<const f4*>(row + base);
#pragma unroll
        for (int j = 0; j < 4; ++j)
            if (x[j] > v) { v = x[j]; vi = base + j; }
    }
#pragma unroll
    for (int off = 16; off > 0; off >>= 1) {
        const float ov = __shfl_xor(v, off);
        const int   oi = __shfl_xor(vi, off);
        if (ov > v || (ov == v && oi < vi)) { v = ov; vi = oi; }
    }
    const int c    = r & (NCLS - 1);
    const int flat = vi + c * NCLASSES;
    f4 t;
#pragma unroll
    for (int j = 0; j < 4; ++j)
        t[j] = emb[(size_t)(4 * hl + j) * NEMB + flat];
    reinterpret_cast<f4*>(out + (size_t)r * EMBD)[hl] = t;
}

extern "C" void kernel_launch(void* const* d_in, const int* in_sizes, int n_in,
                              void* d_out, int out_size, void* d_ws, size_t ws_size,
                              hipStream_t stream) {
    const float* onehot = (const float*)d_in[0];   // (4096, 32, 512) f32
    const float* emb    = (const float*)d_in[1];   // (128, 16384)   f32
    float* out          = (float*)d_out;           // (4096, 4096)   f32

    const size_t embT_bytes = (size_t)NEMB * EMBD * sizeof(float);  // 8.4 MB
    const size_t idx_bytes  = (size_t)NROWS * sizeof(int);          // 512 KB

    if (ws_size >= embT_bytes + idx_bytes) {
        float* embT = (float*)d_ws;
        int*   idx  = (int*)((char*)d_ws + embT_bytes);

        vq_tr_argmax<<<TRBLOCKS + NROWS / 8, 256, 0, stream>>>(
            onehot, emb, embT, idx);
        vq_gather<<<BBLOCKS, 256, 0, stream>>>(idx, embT, out);
    } else {
        vq_fused_cols<<<NROWS / 8, 256, 0, stream>>>(onehot, emb, out);
    }
}

// Round 9
// 60.103 us; speedup vs baseline: 1.1987x; 1.1987x over previous
//
#include <hip/hip_runtime.h>

#define BATCH      4096
#define NCLS       32
#define NCLASSES   512
#define EMBD       128
#define NEMB       16384                 // NCLS * NCLASSES
#define NROWS      (BATCH * NCLS)        // 131072
#define TRBLOCKS   ((NEMB / 32) * (EMBD / 32))   // 2048 transpose blocks
#define BBLOCKS    (NROWS / 8)           // 16384 gather blocks

typedef float f4 __attribute__((ext_vector_type(4)));

// ---------------------------------------------------------------------------
// Kernel A: heterogeneous grid (R6 config — best measured).
//   blocks [0, TRBLOCKS)          : transpose emb (EMBD x NEMB) -> embT
//   blocks [TRBLOCKS, +NROWS/8)   : streaming argmax, half-wave per row
// PLAIN loads on the onehot stream: R6 A/B showed NT loads cost ~4.6us.
// ---------------------------------------------------------------------------
__global__ __launch_bounds__(256) void vq_tr_argmax(
    const float* __restrict__ onehot, const float* __restrict__ emb,
    float* __restrict__ embT, int* __restrict__ idxout) {

    if (blockIdx.x < TRBLOCKS) {
        __shared__ float tile[32][33];
        const int e0 = (blockIdx.x & (NEMB / 32 - 1)) * 32;
        const int d0 = (blockIdx.x / (NEMB / 32)) * 32;
        const int tx = threadIdx.x & 31;
        const int ty = threadIdx.x >> 5;
#pragma unroll
        for (int k = 0; k < 32; k += 8)
            tile[ty + k][tx] = emb[(size_t)(d0 + ty + k) * NEMB + (e0 + tx)];
        __syncthreads();
#pragma unroll
        for (int k = 0; k < 32; k += 8)
            embT[(size_t)(e0 + ty + k) * EMBD + (d0 + tx)] = tile[tx][ty + k];
        return;
    }

    const int ab   = blockIdx.x - TRBLOCKS;
    const int wave = threadIdx.x >> 6;
    const int lane = threadIdx.x & 63;
    const int half = lane >> 5;
    const int hl   = lane & 31;
    const int r    = (ab * 4 + wave) * 2 + half;
    const float* row = onehot + (size_t)r * NCLASSES;

    float v  = -INFINITY;
    int   vi = 0;
#pragma unroll
    for (int k = 0; k < 4; ++k) {
        const int base = hl * 4 + k * 128;
        const f4 x = *reinterpret_cast<const f4*>(row + base);   // plain load
#pragma unroll
        for (int j = 0; j < 4; ++j) {
            if (x[j] > v) { v = x[j]; vi = base + j; }   // strict >: first wins
        }
    }
#pragma unroll
    for (int off = 16; off > 0; off >>= 1) {
        const float ov = __shfl_xor(v, off);
        const int   oi = __shfl_xor(vi, off);
        if (ov > v || (ov == v && oi < vi)) { v = ov; vi = oi; }
    }
    if (hl == 0) idxout[r] = vi;
}

// ---------------------------------------------------------------------------
// Kernel B: gather + write, c-clustered XCD swizzle (R6 config).
// NT store is ESSENTIAL (R8 A/B: plain stores cost +12.3us — write stream
// write-allocates in L2 and evicts the embT gather working set).
// ---------------------------------------------------------------------------
__global__ __launch_bounds__(256) void vq_gather(
    const int* __restrict__ idx, const float* __restrict__ embT,
    float* __restrict__ out) {
    const int xcd  = blockIdx.x & 7;
    const int slot = blockIdx.x >> 3;                 // 0..2047
    const int g    = xcd >> 1;                        // c-group 0..3
    const int w    = g + 4 * ((xcd & 1) * (BBLOCKS / 8) + slot);  // bijective

    const int wave = threadIdx.x >> 6;
    const int lane = threadIdx.x & 63;
    const int half = lane >> 5;
    const int hl   = lane & 31;
    const int r    = (w * 4 + wave) * 2 + half;

    const int c    = r & (NCLS - 1);
    const int flat = idx[r] + c * NCLASSES;   // uniform per half: broadcast load

    const f4 val = reinterpret_cast<const f4*>(embT + (size_t)flat * EMBD)[hl];
    __builtin_nontemporal_store(
        val, reinterpret_cast<f4*>(out + (size_t)r * EMBD) + hl);
}

// ---------------------------------------------------------------------------
// Fallback (ws too small): fused argmax + direct column gather.
// ---------------------------------------------------------------------------
__global__ __launch_bounds__(256) void vq_fused_cols(
    const float* __restrict__ onehot, const float* __restrict__ emb,
    float* __restrict__ out) {
    const int wave = threadIdx.x >> 6;
    const int lane = threadIdx.x & 63;
    const int half = lane >> 5;
    const int hl   = lane & 31;
    const int r    = (blockIdx.x * 4 + wave) * 2 + half;
    const float* row = onehot + (size_t)r * NCLASSES;

    float v  = -INFINITY;
    int   vi = 0;
#pragma unroll
    for (int k = 0; k < 4; ++k) {
        const int base = hl * 4 + k * 128;
        const f4 x = *reinterpret_cast<const f4*>(row + base);
#pragma unroll
        for (int j = 0; j < 4; ++j)
            if (x[j] > v) { v = x[j]; vi = base + j; }
    }
#pragma unroll
    for (int off = 16; off > 0; off >>= 1) {
        const float ov = __shfl_xor(v, off);
        const int   oi = __shfl_xor(vi, off);
        if (ov > v || (ov == v && oi < vi)) { v = ov; vi = oi; }
    }
    const int c    = r & (NCLS - 1);
    const int flat = vi + c * NCLASSES;
    f4 t;
#pragma unroll
    for (int j = 0; j < 4; ++j)
        t[j] = emb[(size_t)(4 * hl + j) * NEMB + flat];
    reinterpret_cast<f4*>(out + (size_t)r * EMBD)[hl] = t;
}

extern "C" void kernel_launch(void* const* d_in, const int* in_sizes, int n_in,
                              void* d_out, int out_size, void* d_ws, size_t ws_size,
                              hipStream_t stream) {
    const float* onehot = (const float*)d_in[0];   // (4096, 32, 512) f32
    const float* emb    = (const float*)d_in[1];   // (128, 16384)   f32
    float* out          = (float*)d_out;           // (4096, 4096)   f32

    const size_t embT_bytes = (size_t)NEMB * EMBD * sizeof(float);  // 8.4 MB
    const size_t idx_bytes  = (size_t)NROWS * sizeof(int);          // 512 KB

    if (ws_size >= embT_bytes + idx_bytes) {
        float* embT = (float*)d_ws;
        int*   idx  = (int*)((char*)d_ws + embT_bytes);

        vq_tr_argmax<<<TRBLOCKS + NROWS / 8, 256, 0, stream>>>(
            onehot, emb, embT, idx);
        vq_gather<<<BBLOCKS, 256, 0, stream>>>(idx, embT, out);
    } else {
        vq_fused_cols<<<NROWS / 8, 256, 0, stream>>>(onehot, emb, out);
    }
}